// Round 4
// baseline (2751.570 us; speedup 1.0000x reference)
//
#include <hip/hip_runtime.h>
#include <hip/hip_bf16.h>

typedef _Float16 f16;
typedef __attribute__((ext_vector_type(8))) _Float16 f16x8;
typedef __attribute__((ext_vector_type(4))) float f32x4;

// ---------------------------------------------------------------- helpers
__device__ __forceinline__ float fast_sig(float x) { return 1.f / (1.f + __expf(-x)); }
// tanh via 1 - 2/(e^{2x}+1): saturates cleanly to +/-1, no NaN at extremes
__device__ __forceinline__ float fast_tanh(float x) {
  float e = __expf(2.f * x);
  return 1.f - 2.f / (e + 1.f);
}

// ---------------------------------------------------------------- f32 -> f16 convert
__global__ __launch_bounds__(256) void f2h_kernel(const float* __restrict__ src,
                                                  f16* __restrict__ dst) {
  size_t i = ((size_t)blockIdx.x * 256 + threadIdx.x) * 4;
  float4 v = *(const float4*)(src + i);
  dst[i + 0] = (f16)v.x;
  dst[i + 1] = (f16)v.y;
  dst[i + 2] = (f16)v.z;
  dst[i + 3] = (f16)v.w;
}

// gather embedding rows: xg[m,:] = (f16)emb[ids[m],:]   (one block per m, H=1024)
__global__ __launch_bounds__(256) void gather_rows(const float* __restrict__ emb,
                                                   const int* __restrict__ ids,
                                                   f16* __restrict__ xg) {
  int m = blockIdx.x;
  int i = threadIdx.x * 4;
  const float* src = emb + (size_t)ids[m] * 1024 + i;
  float4 v = *(const float4*)src;
  f16* d = xg + (size_t)m * 1024 + i;
  d[0] = (f16)v.x; d[1] = (f16)v.y; d[2] = (f16)v.z; d[3] = (f16)v.w;
}

// ---------------------------------------------------------------- state init
__global__ __launch_bounds__(256) void init_state(
    const float* __restrict__ h0, const float* __restrict__ c0,
    f16* __restrict__ h1buf, f16* __restrict__ h2slot0,
    float* __restrict__ c1, float* __restrict__ c2) {
  int i = blockIdx.x * 256 + threadIdx.x;  // 256 blocks -> 65536
  h1buf[i] = (f16)h0[i];
  h2slot0[i] = (f16)h0[65536 + i];
  c1[i] = c0[i];
  c2[i] = c0[65536 + i];
}

// ---------------------------------------------------------------- simple direct-global GEMM
// C[m,n] = sum_k A[m,k]*B[n,k] (+bias1+bias2)(tanh). A = A1 rows [*,K1] then A2 for k>=K1.
// B row-major [N, Ktot], all f16. Block = 64x64 tile, 4 waves; wave w owns 16 m-rows.
// MFMA 16x16x32 f16: A-frag A[m=lane&15][k=(lane>>4)*8+j]; D: n=lane&15, m=(lane>>4)*4+q.
template <typename OutT>
__global__ __launch_bounds__(256) void gemm_simple(
    const f16* __restrict__ A1, const f16* __restrict__ A2,
    const f16* __restrict__ Bm,
    const float* __restrict__ bias1, const float* __restrict__ bias2,
    OutT* __restrict__ C, int ldc,
    int K1, int Ktot, int do_tanh) {
  const int tid = threadIdx.x;
  const int lane = tid & 63;
  const int w = tid >> 6;
  const int m0 = blockIdx.y * 64 + w * 16;  // this wave's 16 m-rows
  const int n0 = blockIdx.x * 64;
  const int am = m0 + (lane & 15);
  const int kq = (lane >> 4) * 8;           // quad's k-offset within a 32-chunk
  const int K2 = Ktot - K1;

  f32x4 acc[4];
#pragma unroll
  for (int j = 0; j < 4; j++) acc[j] = (f32x4){0.f, 0.f, 0.f, 0.f};

  for (int k0 = 0; k0 < Ktot; k0 += 32) {
    int k = k0 + kq;
    f16x8 av;
    if (k < K1)
      av = *(const f16x8*)(A1 + (size_t)am * K1 + k);
    else
      av = *(const f16x8*)(A2 + (size_t)am * K2 + (k - K1));
#pragma unroll
    for (int j = 0; j < 4; j++) {
      f16x8 bv = *(const f16x8*)(Bm + (size_t)(n0 + j * 16 + (lane & 15)) * Ktot + k);
      acc[j] = __builtin_amdgcn_mfma_f32_16x16x32_f16(av, bv, acc[j], 0, 0, 0);
    }
  }

  const int r0 = (lane >> 4) * 4;
  const int cc = lane & 15;
#pragma unroll
  for (int j = 0; j < 4; j++) {
    int col = n0 + j * 16 + cc;
    float bv = 0.f;
    if (bias1) bv += bias1[col];
    if (bias2) bv += bias2[col];
#pragma unroll
    for (int q = 0; q < 4; q++) {
      float v = acc[j][q] + bv;
      if (do_tanh) v = fast_tanh(v);
      C[(size_t)(m0 + r0 + q) * ldc + col] = (OutT)v;
    }
  }
}

// ---------------------------------------------------------------- one LSTM layer, one timestep
// gates = A0 @ W0^T (+ A1 @ W1^T) (+ xbias[b]) (+ ba + bb); cell update; h out.
// 256 blocks x 512 threads. block = (mt 0..3 [16 batch rows], ht 0..63 [16 h]).
// wave w: gate g=w&3, K-half kh=w>>2. All 4 gates of a (b,h) tile in one block.
__global__ __launch_bounds__(512) void lstm_step(
    const f16* __restrict__ A0, const f16* __restrict__ W0,   // [64][1024], [4096][1024]
    const f16* __restrict__ A1, const f16* __restrict__ W1,   // optional second pair
    const float* __restrict__ xbias,                          // [64][4096] or null
    const float* __restrict__ ba, const float* __restrict__ bb,// [4096] or null
    float* __restrict__ c,
    f16* __restrict__ hout,
    float* __restrict__ hf_out, float* __restrict__ cf_out, int fin) {
  __shared__ float red[8 * 256];
  const int tid = threadIdx.x;
  const int lane = tid & 63;
  const int w = tid >> 6;
  const int g = w & 3;
  const int kh = w >> 2;
  const int mt = blockIdx.x & 3;
  const int ht = blockIdx.x >> 2;
  const int am = mt * 16 + (lane & 15);             // batch row (A fragment m)
  const int wr = g * 1024 + ht * 16 + (lane & 15);  // weight row (gate-n)
  const int kb = kh * 512 + (lane >> 4) * 8;        // k base for this wave/lane

  f32x4 acc = (f32x4){0.f, 0.f, 0.f, 0.f};
#pragma unroll 4
  for (int ks = 0; ks < 16; ks++) {
    int k = kb + ks * 32;
    f16x8 av = *(const f16x8*)(A0 + (size_t)am * 1024 + k);
    f16x8 bv = *(const f16x8*)(W0 + (size_t)wr * 1024 + k);
    acc = __builtin_amdgcn_mfma_f32_16x16x32_f16(av, bv, acc, 0, 0, 0);
  }
  if (A1) {
#pragma unroll 4
    for (int ks = 0; ks < 16; ks++) {
      int k = kb + ks * 32;
      f16x8 av = *(const f16x8*)(A1 + (size_t)am * 1024 + k);
      f16x8 bv = *(const f16x8*)(W1 + (size_t)wr * 1024 + k);
      acc = __builtin_amdgcn_mfma_f32_16x16x32_f16(av, bv, acc, 0, 0, 0);
    }
  }
  // D element (m,n) = ((lane>>4)*4+q, lane&15): store to red[w][m][n]
#pragma unroll
  for (int q = 0; q < 4; q++)
    red[w * 256 + ((lane >> 4) * 4 + q) * 16 + (lane & 15)] = acc[q];
  __syncthreads();

  if (tid < 256) {
    int b = mt * 16 + (tid >> 4);
    int h = ht * 16 + (tid & 15);
    float s0 = red[0 * 256 + tid] + red[4 * 256 + tid];  // gate i
    float s1 = red[1 * 256 + tid] + red[5 * 256 + tid];  // gate f
    float s2 = red[2 * 256 + tid] + red[6 * 256 + tid];  // gate g
    float s3 = red[3 * 256 + tid] + red[7 * 256 + tid];  // gate o
    if (xbias) {
      const float* xb = xbias + (size_t)b * 4096 + h;
      s0 += xb[0];
      s1 += xb[1024];
      s2 += xb[2048];
      s3 += xb[3072];
    }
    if (ba) {
      s0 += ba[h] + bb[h];
      s1 += ba[1024 + h] + bb[1024 + h];
      s2 += ba[2048 + h] + bb[2048 + h];
      s3 += ba[3072 + h] + bb[3072 + h];
    }
    int idx = b * 1024 + h;
    float cp = c[idx];
    float cn_ = fast_sig(s1) * cp + fast_sig(s0) * fast_tanh(s2);
    float hn = fast_sig(s3) * fast_tanh(cn_);
    c[idx] = cn_;
    hout[idx] = (f16)hn;
    if (fin) { hf_out[idx] = hn; cf_out[idx] = cn_; }
  }
}

// ---------------------------------------------------------------- attention scores/softmax/wc
// one block per (t,b): scores[s] = ctx[s,b,:].q ; softmax ; wc = a @ ctx[:,b,:]
// all-f32 VALU math (ctx read from original f32 input; Q stored f32) for accuracy.
__global__ __launch_bounds__(256) void attn_kernel(
    const float* __restrict__ Q,   // [4096][1024] f32
    const float* __restrict__ ctx, // context f32 [S=64][B=64][H=1024]
    f16* __restrict__ wc,          // [4096][1024] f16
    float* __restrict__ attn_out) {// [64][64] (t==63 only)
  const int m = blockIdx.x;
  const int b = m & 63;
  const int t = m >> 6;
  const int tid = threadIdx.x;
  const int lane = tid & 63;
  const int w = tid >> 6;
  __shared__ float s_sc[64];
  __shared__ float s_at[64];

  const float* qp = Q + (size_t)m * 1024 + lane * 16;
  float qf[16];
#pragma unroll
  for (int i = 0; i < 4; i++) {
    float4 v = *(const float4*)(qp + i * 4);
    qf[i * 4 + 0] = v.x; qf[i * 4 + 1] = v.y; qf[i * 4 + 2] = v.z; qf[i * 4 + 3] = v.w;
  }

  // scores: wave w handles s in [w*16, w*16+16)
  for (int si = 0; si < 16; si++) {
    int s = w * 16 + si;
    const float* cp = ctx + ((size_t)s * 64 + b) * 1024 + lane * 16;
    float d = 0.f;
#pragma unroll
    for (int i = 0; i < 4; i++) {
      float4 v = *(const float4*)(cp + i * 4);
      d += v.x * qf[i * 4] + v.y * qf[i * 4 + 1] + v.z * qf[i * 4 + 2] + v.w * qf[i * 4 + 3];
    }
#pragma unroll
    for (int off = 32; off > 0; off >>= 1) d += __shfl_down(d, off, 64);
    if (lane == 0) s_sc[s] = d;
  }
  __syncthreads();
  if (w == 0) {
    float v = s_sc[lane];
    float mx = v;
#pragma unroll
    for (int off = 32; off > 0; off >>= 1) mx = fmaxf(mx, __shfl_xor(mx, off, 64));
    float e = __expf(v - mx);
    float sm = e;
#pragma unroll
    for (int off = 32; off > 0; off >>= 1) sm += __shfl_xor(sm, off, 64);
    float a = e / sm;
    s_at[lane] = a;
    if (t == 63) attn_out[b * 64 + lane] = a;
  }
  __syncthreads();
#pragma unroll
  for (int rep = 0; rep < 4; rep++) {
    int h = rep * 256 + tid;
    float acc = 0.f;
    for (int s = 0; s < 64; s++)
      acc += s_at[s] * ctx[((size_t)s * 64 + b) * 1024 + h];
    wc[(size_t)m * 1024 + h] = (f16)acc;
  }
}

// ---------------------------------------------------------------- launch
extern "C" void kernel_launch(void* const* d_in, const int* in_sizes, int n_in,
                              void* d_out, int out_size, void* d_ws, size_t ws_size,
                              hipStream_t stream) {
  const int*   input = (const int*)d_in[0];
  const float* h0    = (const float*)d_in[1];
  const float* c0    = (const float*)d_in[2];
  const float* ctx   = (const float*)d_in[3];
  const float* emb   = (const float*)d_in[4];
  const float* w_ih  = (const float*)d_in[5];
  const float* w_hh  = (const float*)d_in[6];
  const float* b_ih  = (const float*)d_in[7];
  const float* b_hh  = (const float*)d_in[8];
  const float* w_in  = (const float*)d_in[9];
  const float* w_out = (const float*)d_in[10];
  float* out = (float*)d_out;

  char* ws = (char*)d_ws;
  size_t off = 0;
  auto alloc = [&](size_t bytes) {
    char* p = ws + off;
    off += (bytes + 255) & ~(size_t)255;
    return p;
  };
  float* X1     = (float*)alloc((size_t)4096 * 4096 * 4);  // 64 MB (f32 pre-activations)
  f16*   h2hist = (f16*)alloc((size_t)65 * 65536 * 2);     // slot0=init, slot t+1=h2_t
  f16*   h1buf  = (f16*)alloc((size_t)2 * 65536 * 2);      // layer-1 h ping-pong
  float* c1     = (float*)alloc((size_t)65536 * 4);
  float* c2     = (float*)alloc((size_t)65536 * 4);
  float* Q      = (float*)alloc((size_t)4096 * 1024 * 4);  // f32 for attention accuracy
  f16*   wc     = (f16*)alloc((size_t)4096 * 1024 * 2);
  f16*   xg     = (f16*)alloc((size_t)4096 * 1024 * 2);    // gathered emb rows
  f16*   wihh   = (f16*)alloc((size_t)2 * 4096 * 1024 * 2);
  f16*   whhh   = (f16*)alloc((size_t)2 * 4096 * 1024 * 2);
  f16*   winh   = (f16*)alloc((size_t)1024 * 1024 * 2);
  f16*   wouth  = (f16*)alloc((size_t)1024 * 2048 * 2);

  float* outs = out;                              // [T*B][1024]
  float* hf   = out + (size_t)4096 * 1024;        // [2][64][1024]
  float* cf   = hf + 131072;
  float* attn = cf + 131072;                      // [64][64]

  // ---- convert weights to f16; gather+convert embedding rows
  f2h_kernel<<<8192, 256, 0, stream>>>(w_ih, wihh);   // 2*4096*1024
  f2h_kernel<<<8192, 256, 0, stream>>>(w_hh, whhh);
  f2h_kernel<<<1024, 256, 0, stream>>>(w_in, winh);   // 1024*1024
  f2h_kernel<<<2048, 256, 0, stream>>>(w_out, wouth); // 1024*2048
  gather_rows<<<4096, 256, 0, stream>>>(emb, input, xg);

  const f16* Whh1 = whhh;
  const f16* Wih2 = wihh + (size_t)4096 * 1024;
  const f16* Whh2 = whhh + (size_t)4096 * 1024;
  const float* bih2 = b_ih + 4096;
  const float* bhh2 = b_hh + 4096;

  // K0: state init
  init_state<<<256, 256, 0, stream>>>(h0, c0, h1buf, h2hist, c1, c2);

  // K1: X1 = xg @ w_ih1^T + (b_ih1 + b_hh1)   [M=4096,N=4096,K=1024], f32 out
  gemm_simple<float><<<dim3(64, 64), 256, 0, stream>>>(xg, nullptr,
      wihh, b_ih, b_hh, X1, 4096, 1024, 1024, 0);

  // K2: sequential 2-layer LSTM, one launch per (t, layer)
  for (int t = 0; t < 64; t++) {
    f16* h1p = h1buf + (t & 1) * 65536;
    f16* h1n = h1buf + (1 - (t & 1)) * 65536;
    // layer 1: gates = X1[t] + h1_{t-1} @ Whh1^T
    lstm_step<<<256, 512, 0, stream>>>(h1p, Whh1, nullptr, nullptr,
        X1 + (size_t)t * 262144, nullptr, nullptr,
        c1, h1n, hf, cf, t == 63);
    // layer 2: gates = h1_t @ Wih2^T + h2_{t-1} @ Whh2^T + biases
    lstm_step<<<256, 512, 0, stream>>>(h1n, Wih2,
        h2hist + (size_t)t * 65536, Whh2,
        nullptr, bih2, bhh2,
        c2, h2hist + (size_t)(t + 1) * 65536, hf + 65536, cf + 65536, t == 63);
  }

  // K3: Q = H2_all @ w_in^T   [M=4096,N=1024,K=1024], f32 out
  gemm_simple<float><<<dim3(16, 64), 256, 0, stream>>>(h2hist + 65536, nullptr,
      winh, nullptr, nullptr, Q, 1024, 1024, 1024, 0);

  // K4: scores -> softmax -> weighted context (+ final-step attention output), all f32
  attn_kernel<<<4096, 256, 0, stream>>>(Q, ctx, wc, attn);

  // K5: outs = tanh([wc | H2_all] @ w_out^T)   [M=4096,N=1024,K=2048], f32 out
  gemm_simple<float><<<dim3(16, 64), 256, 0, stream>>>(wc, h2hist + 65536,
      wouth, nullptr, nullptr, outs, 1024, 1024, 2048, 1);
}